// Round 4
// baseline (7361.227 us; speedup 1.0000x reference)
//
#include <hip/hip_runtime.h>
#include <math.h>

#define T_SEQ 1024
#define B_SZ  128
#define I_SZ  256
#define H_SZ  512
#define G_SZ  1536  // 3*H

#define NBS   8     // batch slices (clusters)
#define MB    16    // batch per block
#define NHS   4     // h slices = blocks per cluster
#define HB    128   // h cols per block
#define GB    384   // gate cols per block (3*HB)
#define NTHR  768   // 12 waves

typedef _Float16 f16;
typedef _Float16 half8 __attribute__((ext_vector_type(8)));
typedef _Float16 f16x4 __attribute__((ext_vector_type(4)));
typedef float f32x4 __attribute__((ext_vector_type(4)));

// ---- coherent (MALL-level) ops: bypass L1/L2 so no cache fences needed ----
__device__ __forceinline__ f32x4 load_f4_cohere_nw(const void* p) {
    f32x4 v;
    asm volatile("global_load_dwordx4 %0, %1, off sc0 sc1" : "=v"(v) : "v"(p));
    return v;
}
__device__ __forceinline__ f16x4 load_f16x4_nw(const void* p) {
    f16x4 v;
    asm volatile("global_load_dwordx2 %0, %1, off" : "=v"(v) : "v"(p));
    return v;
}
__device__ __forceinline__ unsigned load_u32_cohere(const void* p) {
    unsigned v;
    asm volatile("global_load_dword %0, %1, off sc0 sc1\n\ts_waitcnt vmcnt(0)"
                 : "=v"(v) : "v"(p) : "memory");
    return v;
}
__device__ __forceinline__ void store_u32_cohere(void* p, unsigned v) {
    asm volatile("global_store_dword %0, %1, off sc0 sc1"
                 :: "v"(p), "v"(v) : "memory");
}
__device__ __forceinline__ void wait_vm0() {
    asm volatile("s_waitcnt vmcnt(0)" ::: "memory");
    __builtin_amdgcn_sched_barrier(0);
}
__device__ __forceinline__ void wait_vm2() {   // allow 2 outstanding (the gi loads)
    asm volatile("s_waitcnt vmcnt(2)" ::: "memory");
    __builtin_amdgcn_sched_barrier(0);
}

// ---------------------------------------------------------------------------
// Setup: w_ih -> f16 (same layout [g][i]); w_hh -> f16 gru slices
// [hs][GB][512] (k-contiguous); h0 -> f16 broadcast; zero flags.
// ---------------------------------------------------------------------------
__global__ void setup_kernel(const float* __restrict__ w_ih,
                             const float* __restrict__ w_hh,
                             const float* __restrict__ h0,
                             f16* __restrict__ wp16,
                             f16* __restrict__ wf16,
                             f16* __restrict__ hbuf0,
                             unsigned int* __restrict__ flags) {
    const int i0 = blockIdx.x * blockDim.x + threadIdx.x;
    const int stride = gridDim.x * blockDim.x;
    for (int i = i0; i < I_SZ * G_SZ; i += stride)
        wp16[i] = (f16)w_ih[i];
    for (int i = i0; i < NHS * GB * H_SZ; i += stride) {
        int hs  = i / (GB * H_SZ);
        int rem = i % (GB * H_SZ);
        int gl = rem / H_SZ, k = rem % H_SZ;
        int gate = gl >> 7, c = gl & 127;
        int gg = gate * H_SZ + hs * HB + c;
        wf16[i] = (f16)w_hh[(size_t)gg * H_SZ + k];
    }
    for (int i = i0; i < B_SZ * H_SZ; i += stride)
        hbuf0[i] = (f16)h0[i % H_SZ];
    if (i0 < NBS * NHS * 16) flags[i0] = 0;
}

// ---------------------------------------------------------------------------
// Input projection, f16 MFMA. Per block: one t, 384 g-cols, all 128 b.
// gi16[t][g][b] = f16( sum_i w_ih[g][i]*x[b][t][i] + b_ih[g] )
// MFMA fragment mapping copied from the verified gru kernel:
//   A-operand (m=g): lane&15 picks row, k contiguous. B (n=b): lane&15 picks
//   col from LDS. D: row = (lane>>4)*4+r, col = lane&15.
// ---------------------------------------------------------------------------
__global__ __launch_bounds__(512, 1)
void proj_kernel(const float* __restrict__ x,
                 const f16* __restrict__ wp16,
                 const float* __restrict__ b_ih,
                 f16* __restrict__ gi16) {
    const int t  = blockIdx.x >> 2;
    const int g0 = (blockIdx.x & 3) * GB;
    const int tid  = threadIdx.x;
    const int wid  = tid >> 6;
    const int lane = tid & 63;
    const int col  = lane & 15;
    const int krow = lane >> 4;

    __shared__ __align__(16) unsigned char x_lds[128 * 512];  // [b][k] f16, 64 KB

    // stage x_t -> f16 LDS (swizzled rows of 512 B)
    #pragma unroll
    for (int j = 0; j < 8; ++j) {
        int idx = tid + j * 512;
        int b = idx >> 5, k16 = idx & 31;
        const float* xp = x + ((size_t)b * T_SEQ + t) * I_SZ + k16 * 8;
        float4 v0 = *reinterpret_cast<const float4*>(xp);
        float4 v1 = *reinterpret_cast<const float4*>(xp + 4);
        half8 hv;
        hv[0] = (f16)v0.x; hv[1] = (f16)v0.y; hv[2] = (f16)v0.z; hv[3] = (f16)v0.w;
        hv[4] = (f16)v1.x; hv[5] = (f16)v1.y; hv[6] = (f16)v1.z; hv[7] = (f16)v1.w;
        unsigned addr = ((unsigned)(b * 512 + k16 * 16)) ^ (((unsigned)(b & 7)) << 4);
        *reinterpret_cast<half8*>(x_lds + addr) = hv;
    }

    // A fragments (weights): 3 m-tiles x 8 k-tiles per wave
    const int gw0 = g0 + wid * 48;
    half8 af[3][8];
    #pragma unroll
    for (int m = 0; m < 3; ++m)
        #pragma unroll
        for (int k = 0; k < 8; ++k)
            af[m][k] = *reinterpret_cast<const half8*>(
                wp16 + (size_t)(gw0 + m * 16 + col) * I_SZ + k * 32 + krow * 8);

    float bias[3][4];
    #pragma unroll
    for (int m = 0; m < 3; ++m)
        #pragma unroll
        for (int r = 0; r < 4; ++r)
            bias[m][r] = b_ih[gw0 + m * 16 + krow * 4 + r];

    __syncthreads();

    #pragma unroll
    for (int nt = 0; nt < 8; ++nt) {
        const int b0 = nt * 16;
        f32x4 acc0 = {0.f,0.f,0.f,0.f}, acc1 = {0.f,0.f,0.f,0.f}, acc2 = {0.f,0.f,0.f,0.f};
        const int brow = b0 + col;
        const unsigned bswz = ((unsigned)(brow & 7)) << 4;
        #pragma unroll
        for (int k = 0; k < 8; ++k) {
            half8 bf = *reinterpret_cast<const half8*>(
                x_lds + (((unsigned)(brow * 512 + k * 64 + krow * 16)) ^ bswz));
            acc0 = __builtin_amdgcn_mfma_f32_16x16x32_f16(af[0][k], bf, acc0, 0, 0, 0);
            acc1 = __builtin_amdgcn_mfma_f32_16x16x32_f16(af[1][k], bf, acc1, 0, 0, 0);
            acc2 = __builtin_amdgcn_mfma_f32_16x16x32_f16(af[2][k], bf, acc2, 0, 0, 0);
        }
        #pragma unroll
        for (int r = 0; r < 4; ++r) {
            int gr = gw0 + krow * 4 + r;
            gi16[((size_t)t * G_SZ + gr)      * B_SZ + brow] = (f16)(acc0[r] + bias[0][r]);
            gi16[((size_t)t * G_SZ + gr + 16) * B_SZ + brow] = (f16)(acc1[r] + bias[1][r]);
            gi16[((size_t)t * G_SZ + gr + 32) * B_SZ + brow] = (f16)(acc2[r] + bias[2][r]);
        }
    }
}

// ---------------------------------------------------------------------------
// Persistent GRU. 32 blocks = 8 batch-slices x 4 h-slices. Weights in VGPR
// (2 col-tiles x 16 K-tiles = 128 VGPR/lane). Per-cluster barrier: one flag
// line per block (plain sc0|sc1 store), wave-0 parallel poll. gi prefetched
// with counted vmcnt so HBM latency hides under the MFMA phase.
// ---------------------------------------------------------------------------
__global__ __launch_bounds__(NTHR, 1)
void gru_persist(const f16* __restrict__ gi,      // [T][G][B] f16
                 const f16* __restrict__ wf16,    // [NHS][GB][512]
                 const float* __restrict__ h0,
                 const float* __restrict__ b_hh,
                 f16* __restrict__ hbuf0,
                 f16* __restrict__ hbuf1,
                 unsigned int* __restrict__ flags,
                 float* __restrict__ out) {
    const int bs  = blockIdx.x & (NBS - 1);
    const int hs  = blockIdx.x >> 3;
    const int tid = threadIdx.x;

    __shared__ __align__(16) unsigned char h_lds[MB * H_SZ * 2];  // 16 KB
    __shared__ float act_r[MB][HB + 1];
    __shared__ float act_z[MB][HB + 1];
    __shared__ float act_n[MB][HB + 1];
    __shared__ float act_i[MB][HB + 1];

    const int wid  = tid >> 6;
    const int lane = tid & 63;
    const int gate = wid >> 2;          // 0=r,1=z,2=n
    const int sub  = wid & 3;
    const int col  = lane & 15;
    const int krow = lane >> 4;
    const int c0 = sub * 32 + col;      // two col-tiles per wave
    const int c1 = c0 + 16;
    const int gg0 = gate * H_SZ + hs * HB + c0;
    const int gg1 = gate * H_SZ + hs * HB + c1;

    // B fragments in registers: 2 tiles x 16 K x half8 = 128 VGPR
    half8 bf0[16], bf1[16];
    {
        const f16* w0 = wf16 + ((size_t)hs * GB + gate * HB + c0) * H_SZ + krow * 8;
        const f16* w1 = wf16 + ((size_t)hs * GB + gate * HB + c1) * H_SZ + krow * 8;
        #pragma unroll
        for (int kk = 0; kk < 16; ++kk) {
            bf0[kk] = *reinterpret_cast<const half8*>(w0 + kk * 32);
            bf1[kk] = *reinterpret_cast<const half8*>(w1 + kk * 32);
        }
    }
    const float bias0 = b_hh[gg0];
    const float bias1 = b_hh[gg1];

    // combine ownership: 2x2 outputs (b0c..+1, c0c..+1), threads 0..511
    const int b0c = 2 * (tid >> 6);
    const int c0c = 2 * (tid & 63);
    float hm00 = 0.f, hm01 = 0.f, hm10 = 0.f, hm11 = 0.f;
    if (tid < 512) {
        hm00 = h0[hs * HB + c0c]; hm01 = h0[hs * HB + c0c + 1];
        hm10 = hm00;              hm11 = hm01;
    }

    const unsigned a_base = (unsigned)(col * 1024 + krow * 16);
    const unsigned a_swz  = ((unsigned)(col & 7)) << 4;

    unsigned int* myflag = flags + (size_t)(bs * NHS + hs) * 16;

    for (int t = 0; t < T_SEQ; ++t) {
        const f16* hin = (t & 1) ? hbuf1 : hbuf0;
        f16*      hout = (t & 1) ? hbuf0 : hbuf1;

        // ---- issue h loads (MALL), then gi loads; wait only for h ----
        const int i0 = tid, i1 = tid + NTHR;       // 1024 granules of 16 B
        f32x4 hv0 = load_f4_cohere_nw(
            hin + (size_t)(bs * MB + (i0 >> 6)) * H_SZ + (i0 & 63) * 8);
        f32x4 hv1;
        if (i1 < 1024)                               // waves 0-3 only
            hv1 = load_f4_cohere_nw(
                hin + (size_t)(bs * MB + (i1 >> 6)) * H_SZ + (i1 & 63) * 8);
        f16x4 gv0 = load_f16x4_nw(
            gi + ((size_t)t * G_SZ + gg0) * B_SZ + bs * MB + krow * 4);
        f16x4 gv1 = load_f16x4_nw(
            gi + ((size_t)t * G_SZ + gg1) * B_SZ + bs * MB + krow * 4);
        wait_vm2();   // h done; gi still in flight

        {
            unsigned a0 = ((unsigned)((i0 >> 6) * 1024 + (i0 & 63) * 16))
                          ^ (((unsigned)((i0 >> 6) & 7)) << 4);
            *reinterpret_cast<f32x4*>(h_lds + a0) = hv0;
            if (i1 < 1024) {
                unsigned a1 = ((unsigned)((i1 >> 6) * 1024 + (i1 & 63) * 16))
                              ^ (((unsigned)((i1 >> 6) & 7)) << 4);
                *reinterpret_cast<f32x4*>(h_lds + a1) = hv1;
            }
        }
        __syncthreads();

        // ---- gh: 16 batch x 32 cols, K=512 ----
        f32x4 acc0 = {0.f,0.f,0.f,0.f}, acc1 = {0.f,0.f,0.f,0.f};
        #pragma unroll
        for (int kk = 0; kk < 16; ++kk) {
            half8 av = *reinterpret_cast<const half8*>(
                h_lds + ((a_base + kk * 64) ^ a_swz));
            acc0 = __builtin_amdgcn_mfma_f32_16x16x32_f16(av, bf0[kk], acc0, 0, 0, 0);
            acc1 = __builtin_amdgcn_mfma_f32_16x16x32_f16(av, bf1[kk], acc1, 0, 0, 0);
        }

        wait_vm0();   // gi arrived (drains everything; sched_barrier inside)

        // ---- activations ----
        if (gate == 0) {
            #pragma unroll
            for (int r = 0; r < 4; ++r) {
                int b = krow * 4 + r;
                act_r[b][c0] = 1.f / (1.f + __expf(-(acc0[r] + bias0 + (float)gv0[r])));
                act_r[b][c1] = 1.f / (1.f + __expf(-(acc1[r] + bias1 + (float)gv1[r])));
            }
        } else if (gate == 1) {
            #pragma unroll
            for (int r = 0; r < 4; ++r) {
                int b = krow * 4 + r;
                act_z[b][c0] = 1.f / (1.f + __expf(-(acc0[r] + bias0 + (float)gv0[r])));
                act_z[b][c1] = 1.f / (1.f + __expf(-(acc1[r] + bias1 + (float)gv1[r])));
            }
        } else {
            #pragma unroll
            for (int r = 0; r < 4; ++r) {
                int b = krow * 4 + r;
                act_n[b][c0] = acc0[r] + bias0;  act_i[b][c0] = (float)gv0[r];
                act_n[b][c1] = acc1[r] + bias1;  act_i[b][c1] = (float)gv1[r];
            }
        }
        __syncthreads();

        // ---- combine (threads 0..511): 2 batch x 2 cols each ----
        if (tid < 512) {
            float r00 = act_r[b0c][c0c],     r01 = act_r[b0c][c0c + 1];
            float r10 = act_r[b0c + 1][c0c], r11 = act_r[b0c + 1][c0c + 1];
            float z00 = act_z[b0c][c0c],     z01 = act_z[b0c][c0c + 1];
            float z10 = act_z[b0c + 1][c0c], z11 = act_z[b0c + 1][c0c + 1];
            float a00 = act_i[b0c][c0c]         + r00 * act_n[b0c][c0c];
            float a01 = act_i[b0c][c0c + 1]     + r01 * act_n[b0c][c0c + 1];
            float a10 = act_i[b0c + 1][c0c]     + r10 * act_n[b0c + 1][c0c];
            float a11 = act_i[b0c + 1][c0c + 1] + r11 * act_n[b0c + 1][c0c + 1];
            float n00 = 1.f - 2.f / (__expf(2.f * a00) + 1.f);
            float n01 = 1.f - 2.f / (__expf(2.f * a01) + 1.f);
            float n10 = 1.f - 2.f / (__expf(2.f * a10) + 1.f);
            float n11 = 1.f - 2.f / (__expf(2.f * a11) + 1.f);
            float h00 = (1.f - z00) * n00 + z00 * hm00;
            float h01 = (1.f - z01) * n01 + z01 * hm01;
            float h10 = (1.f - z10) * n10 + z10 * hm10;
            float h11 = (1.f - z11) * n11 + z11 * hm11;
            h00 = fminf(fmaxf(h00, -5.f), 5.f);
            h01 = fminf(fmaxf(h01, -5.f), 5.f);
            h10 = fminf(fmaxf(h10, -5.f), 5.f);
            h11 = fminf(fmaxf(h11, -5.f), 5.f);
            hm00 = h00; hm01 = h01; hm10 = h10; hm11 = h11;

            const int bg0 = bs * MB + b0c;
            const int hg  = hs * HB + c0c;
            *reinterpret_cast<float2*>(
                out + ((size_t)bg0 * T_SEQ + t) * H_SZ + hg) = make_float2(h00, h01);
            *reinterpret_cast<float2*>(
                out + ((size_t)(bg0 + 1) * T_SEQ + t) * H_SZ + hg) = make_float2(h10, h11);

            f16 p00 = (f16)h00, p01 = (f16)h01, p10 = (f16)h10, p11 = (f16)h11;
            unsigned pk0 = (unsigned)__builtin_bit_cast(unsigned short, p00)
                         | ((unsigned)__builtin_bit_cast(unsigned short, p01) << 16);
            unsigned pk1 = (unsigned)__builtin_bit_cast(unsigned short, p10)
                         | ((unsigned)__builtin_bit_cast(unsigned short, p11) << 16);
            store_u32_cohere(hout + (size_t)bg0 * H_SZ + hg, pk0);
            store_u32_cohere(hout + (size_t)(bg0 + 1) * H_SZ + hg, pk1);

            if (t == T_SEQ - 1) {
                size_t tail = (size_t)B_SZ * T_SEQ * H_SZ;
                *reinterpret_cast<float2*>(
                    out + tail + (size_t)bg0 * H_SZ + hg) = make_float2(h00, h01);
                *reinterpret_cast<float2*>(
                    out + tail + (size_t)(bg0 + 1) * H_SZ + hg) = make_float2(h10, h11);
            }
        }

        // ---- cluster barrier: per-wave drain, flag store, parallel poll ----
        wait_vm0();
        __syncthreads();
        if (t < T_SEQ - 1) {
            if (tid == 0) store_u32_cohere(myflag, (unsigned)(t + 1));
            if (tid < 64) {
                const unsigned int* fp =
                    flags + (size_t)(bs * NHS + (tid & 3)) * 16;
                int guard = 0;
                unsigned v;
                do {
                    v = load_u32_cohere(fp);
                } while (__any(v < (unsigned)(t + 1)) && ++guard < (1 << 20));
            }
            __syncthreads();
        }
    }
}

// ---------------------------------------------------------------------------
extern "C" void kernel_launch(void* const* d_in, const int* in_sizes, int n_in,
                              void* d_out, int out_size, void* d_ws, size_t ws_size,
                              hipStream_t stream) {
    const float* x    = (const float*)d_in[0];
    const float* h0   = (const float*)d_in[1];
    const float* w_ih = (const float*)d_in[2];
    const float* w_hh = (const float*)d_in[3];
    const float* b_ih = (const float*)d_in[4];
    const float* b_hh = (const float*)d_in[5];
    float* out = (float*)d_out;

    char* p = (char*)d_ws;
    f16* wp16  = (f16*)p;                 p += (size_t)I_SZ * G_SZ * 2;        // 768 KB
    f16* wf16  = (f16*)p;                 p += (size_t)NHS * GB * H_SZ * 2;    // 1.5 MB
    f16* hbuf0 = (f16*)p;                 p += (size_t)B_SZ * H_SZ * 2;        // 128 KB
    f16* hbuf1 = (f16*)p;                 p += (size_t)B_SZ * H_SZ * 2;        // 128 KB
    unsigned int* flags = (unsigned int*)p; p += (size_t)NBS * NHS * 16 * 4;   // 2 KB
    f16* gi = (f16*)p;                    // [T][G][B] f16 = 402 MB (ws >= 810 MB proven)

    setup_kernel<<<512, 256, 0, stream>>>(w_ih, w_hh, h0, wp16, wf16, hbuf0, flags);

    proj_kernel<<<T_SEQ * 4, 512, 0, stream>>>(x, wp16, b_ih, gi);

    gru_persist<<<NBS * NHS, NTHR, 0, stream>>>(gi, wf16, h0, b_hh,
                                                hbuf0, hbuf1, flags, out);
}

// Round 5
// 3091.109 us; speedup vs baseline: 2.3814x; 2.3814x over previous
//
#include <hip/hip_runtime.h>
#include <math.h>

#define T_SEQ 1024
#define B_SZ  128
#define I_SZ  256
#define H_SZ  512
#define G_SZ  1536  // 3*H

#define NBS   8     // batch slices (clusters)
#define MB    16    // batch per block
#define NHS   16    // h slices = blocks per cluster
#define HB    32    // h cols per block
#define GB    96    // gate cols per block (3*HB)
#define NTHR  384   // 6 waves
#define PGB   384   // proj: gate cols per block

typedef _Float16 f16;
typedef _Float16 half8 __attribute__((ext_vector_type(8)));
typedef _Float16 f16x4 __attribute__((ext_vector_type(4)));
typedef float f32x4 __attribute__((ext_vector_type(4)));

// ---- coherent (MALL-level) ops: bypass L1/L2, no cache fences needed ----
__device__ __forceinline__ f32x4 load_f4_cohere_nw(const void* p) {
    f32x4 v;
    asm volatile("global_load_dwordx4 %0, %1, off sc0 sc1" : "=v"(v) : "v"(p));
    return v;
}
__device__ __forceinline__ f16x4 load_f16x4_nw(const void* p) {
    f16x4 v;
    asm volatile("global_load_dwordx2 %0, %1, off" : "=v"(v) : "v"(p));
    return v;
}
__device__ __forceinline__ unsigned load_u32_cohere(const void* p) {
    unsigned v;
    asm volatile("global_load_dword %0, %1, off sc0 sc1\n\ts_waitcnt vmcnt(0)"
                 : "=v"(v) : "v"(p) : "memory");
    return v;
}
__device__ __forceinline__ void store_u32_cohere(void* p, unsigned v) {
    asm volatile("global_store_dword %0, %1, off sc0 sc1"
                 :: "v"(p), "v"(v) : "memory");
}
__device__ __forceinline__ void wait_vm0() {
    asm volatile("s_waitcnt vmcnt(0)" ::: "memory");
    __builtin_amdgcn_sched_barrier(0);
}
__device__ __forceinline__ void wait_vm1() {
    asm volatile("s_waitcnt vmcnt(1)" ::: "memory");
    __builtin_amdgcn_sched_barrier(0);
}

// ---------------------------------------------------------------------------
// Setup: w_ih -> f16 [g][i]; w_hh -> f16 slices [hs=16][GB=96][512]
// (k-contiguous per gate-col); h0 -> f16 broadcast; zero flags (2048).
// ---------------------------------------------------------------------------
__global__ void setup_kernel(const float* __restrict__ w_ih,
                             const float* __restrict__ w_hh,
                             const float* __restrict__ h0,
                             f16* __restrict__ wp16,
                             f16* __restrict__ wf16,
                             f16* __restrict__ hbuf0,
                             unsigned int* __restrict__ flags) {
    const int i0 = blockIdx.x * blockDim.x + threadIdx.x;
    const int stride = gridDim.x * blockDim.x;
    for (int i = i0; i < I_SZ * G_SZ; i += stride)
        wp16[i] = (f16)w_ih[i];
    for (int i = i0; i < NHS * GB * H_SZ; i += stride) {
        int hs  = i / (GB * H_SZ);
        int rem = i % (GB * H_SZ);
        int gl = rem / H_SZ, k = rem % H_SZ;
        int gate = gl >> 5, c = gl & 31;
        int gg = gate * H_SZ + hs * HB + c;
        wf16[i] = (f16)w_hh[(size_t)gg * H_SZ + k];
    }
    for (int i = i0; i < B_SZ * H_SZ; i += stride)
        hbuf0[i] = (f16)h0[i % H_SZ];
    if (i0 < NBS * NHS * 16) flags[i0] = 0;
}

// ---------------------------------------------------------------------------
// Input projection, f16 MFMA (verified in round 4, unchanged).
// gi16[t][g][b] = f16( sum_i w_ih[g][i]*x[b][t][i] + b_ih[g] )
// ---------------------------------------------------------------------------
__global__ __launch_bounds__(512, 1)
void proj_kernel(const float* __restrict__ x,
                 const f16* __restrict__ wp16,
                 const float* __restrict__ b_ih,
                 f16* __restrict__ gi16) {
    const int t  = blockIdx.x >> 2;
    const int g0 = (blockIdx.x & 3) * PGB;
    const int tid  = threadIdx.x;
    const int wid  = tid >> 6;
    const int lane = tid & 63;
    const int col  = lane & 15;
    const int krow = lane >> 4;

    __shared__ __align__(16) unsigned char x_lds[128 * 512];  // [b][k] f16, 64 KB

    #pragma unroll
    for (int j = 0; j < 8; ++j) {
        int idx = tid + j * 512;
        int b = idx >> 5, k16 = idx & 31;
        const float* xp = x + ((size_t)b * T_SEQ + t) * I_SZ + k16 * 8;
        float4 v0 = *reinterpret_cast<const float4*>(xp);
        float4 v1 = *reinterpret_cast<const float4*>(xp + 4);
        half8 hv;
        hv[0] = (f16)v0.x; hv[1] = (f16)v0.y; hv[2] = (f16)v0.z; hv[3] = (f16)v0.w;
        hv[4] = (f16)v1.x; hv[5] = (f16)v1.y; hv[6] = (f16)v1.z; hv[7] = (f16)v1.w;
        unsigned addr = ((unsigned)(b * 512 + k16 * 16)) ^ (((unsigned)(b & 7)) << 4);
        *reinterpret_cast<half8*>(x_lds + addr) = hv;
    }

    const int gw0 = g0 + wid * 48;
    half8 af[3][8];
    #pragma unroll
    for (int m = 0; m < 3; ++m)
        #pragma unroll
        for (int k = 0; k < 8; ++k)
            af[m][k] = *reinterpret_cast<const half8*>(
                wp16 + (size_t)(gw0 + m * 16 + col) * I_SZ + k * 32 + krow * 8);

    float bias[3][4];
    #pragma unroll
    for (int m = 0; m < 3; ++m)
        #pragma unroll
        for (int r = 0; r < 4; ++r)
            bias[m][r] = b_ih[gw0 + m * 16 + krow * 4 + r];

    __syncthreads();

    #pragma unroll
    for (int nt = 0; nt < 8; ++nt) {
        const int b0 = nt * 16;
        f32x4 acc0 = {0.f,0.f,0.f,0.f}, acc1 = {0.f,0.f,0.f,0.f}, acc2 = {0.f,0.f,0.f,0.f};
        const int brow = b0 + col;
        const unsigned bswz = ((unsigned)(brow & 7)) << 4;
        #pragma unroll
        for (int k = 0; k < 8; ++k) {
            half8 bf = *reinterpret_cast<const half8*>(
                x_lds + (((unsigned)(brow * 512 + k * 64 + krow * 16)) ^ bswz));
            acc0 = __builtin_amdgcn_mfma_f32_16x16x32_f16(af[0][k], bf, acc0, 0, 0, 0);
            acc1 = __builtin_amdgcn_mfma_f32_16x16x32_f16(af[1][k], bf, acc1, 0, 0, 0);
            acc2 = __builtin_amdgcn_mfma_f32_16x16x32_f16(af[2][k], bf, acc2, 0, 0, 0);
        }
        #pragma unroll
        for (int r = 0; r < 4; ++r) {
            int gr = gw0 + krow * 4 + r;
            gi16[((size_t)t * G_SZ + gr)      * B_SZ + brow] = (f16)(acc0[r] + bias[0][r]);
            gi16[((size_t)t * G_SZ + gr + 16) * B_SZ + brow] = (f16)(acc1[r] + bias[1][r]);
            gi16[((size_t)t * G_SZ + gr + 32) * B_SZ + brow] = (f16)(acc2[r] + bias[2][r]);
        }
    }
}

// ---------------------------------------------------------------------------
// Persistent GRU. 128 blocks = 8 batch-slices x 16 h-slices (round-3 geometry:
// 64 VGPR of B-fragments stays register-resident). Barrier = per-block flag
// line (sc0|sc1 store) + 16-lane parallel poll; zero serialized RMWs.
// gi (f16) load overlapped with h via counted vmcnt; out store drains in
// background (h store issued first, vmcnt(1) before the flag).
// ---------------------------------------------------------------------------
__global__ __launch_bounds__(NTHR, 1)
void gru_persist(const f16* __restrict__ gi,      // [T][G][B] f16
                 const f16* __restrict__ wf16,    // [NHS][GB][512]
                 const float* __restrict__ h0,
                 const float* __restrict__ b_hh,
                 f16* __restrict__ hbuf0,
                 f16* __restrict__ hbuf1,
                 unsigned int* __restrict__ flags,
                 float* __restrict__ out) {
    const int bs  = blockIdx.x & (NBS - 1);
    const int hs  = blockIdx.x >> 3;   // 0..15
    const int tid = threadIdx.x;

    __shared__ __align__(16) unsigned char h_lds[MB * H_SZ * 2];  // 16 KB
    __shared__ float act_r[MB][HB + 1];
    __shared__ float act_z[MB][HB + 1];
    __shared__ float act_n[MB][HB + 1];
    __shared__ float act_i[MB][HB + 1];

    const int wid  = tid >> 6;
    const int lane = tid & 63;
    const int gate = wid >> 1;          // 0=r, 1=z, 2=n
    const int sub  = wid & 1;
    const int col  = lane & 15;
    const int krow = lane >> 4;
    const int c_local = sub * 16 + col;               // 0..31
    const int g_glob  = gate * H_SZ + hs * HB + c_local;

    // B fragments: 16 K-tiles x half8 = 64 VGPR (register-resident, as in R3)
    half8 bfrag[16];
    {
        const f16* wp = wf16 + ((size_t)hs * GB + gate * HB + c_local) * H_SZ
                             + krow * 8;
        #pragma unroll
        for (int kk = 0; kk < 16; ++kk)
            bfrag[kk] = *reinterpret_cast<const half8*>(wp + kk * 32);
    }
    const float bias = b_hh[g_glob];

    // combine ownership (tid<256): batch row cb, col pair (cc, cc+1)
    const int cb = tid >> 4;
    const int cc = (tid & 15) * 2;
    float hm0 = 0.f, hm1 = 0.f;
    if (tid < 256) { hm0 = h0[hs * HB + cc]; hm1 = h0[hs * HB + cc + 1]; }

    const unsigned a_base = (unsigned)(col * 1024 + krow * 16);
    const unsigned a_swz  = ((unsigned)(col & 7)) << 4;

    unsigned int* myflag = flags + (size_t)(bs * NHS + hs) * 16;

    for (int t = 0; t < T_SEQ; ++t) {
        const f16* hin = (t & 1) ? hbuf1 : hbuf0;
        f16*      hout = (t & 1) ? hbuf0 : hbuf1;

        // ---- issue h loads (MALL) then the gi load; wait for h only ----
        const int i0 = tid, i1 = tid + NTHR, i2 = tid + 2 * NTHR;
        f32x4 hv0 = load_f4_cohere_nw(
            hin + (size_t)(bs * MB + (i0 >> 6)) * H_SZ + (i0 & 63) * 8);
        f32x4 hv1 = load_f4_cohere_nw(
            hin + (size_t)(bs * MB + (i1 >> 6)) * H_SZ + (i1 & 63) * 8);
        f32x4 hv2;
        if (i2 < 1024)   // waves 0-3
            hv2 = load_f4_cohere_nw(
                hin + (size_t)(bs * MB + (i2 >> 6)) * H_SZ + (i2 & 63) * 8);
        f16x4 gv = load_f16x4_nw(
            gi + ((size_t)t * G_SZ + g_glob) * B_SZ + bs * MB + krow * 4);
        wait_vm1();   // all h loads done; gi still in flight (uniform per wave)

        {
            unsigned a0 = ((unsigned)((i0 >> 6) * 1024 + (i0 & 63) * 16))
                          ^ (((unsigned)((i0 >> 6) & 7)) << 4);
            *reinterpret_cast<f32x4*>(h_lds + a0) = hv0;
            unsigned a1 = ((unsigned)((i1 >> 6) * 1024 + (i1 & 63) * 16))
                          ^ (((unsigned)((i1 >> 6) & 7)) << 4);
            *reinterpret_cast<f32x4*>(h_lds + a1) = hv1;
            if (i2 < 1024) {
                unsigned a2 = ((unsigned)((i2 >> 6) * 1024 + (i2 & 63) * 16))
                              ^ (((unsigned)((i2 >> 6) & 7)) << 4);
                *reinterpret_cast<f32x4*>(h_lds + a2) = hv2;
            }
        }
        __syncthreads();

        // ---- gh: 16 batch x 16 cols, K=512; gi latency hides under this ----
        f32x4 acc = {0.f, 0.f, 0.f, 0.f};
        #pragma unroll
        for (int kk = 0; kk < 16; ++kk) {
            half8 av = *reinterpret_cast<const half8*>(
                h_lds + ((a_base + kk * 64) ^ a_swz));
            acc = __builtin_amdgcn_mfma_f32_16x16x32_f16(av, bfrag[kk], acc, 0, 0, 0);
        }
        wait_vm0();   // gi arrived

        // ---- per-gate activation to LDS ----
        if (gate == 0) {
            #pragma unroll
            for (int r = 0; r < 4; ++r)
                act_r[krow * 4 + r][c_local] =
                    1.f / (1.f + __expf(-(acc[r] + bias + (float)gv[r])));
        } else if (gate == 1) {
            #pragma unroll
            for (int r = 0; r < 4; ++r)
                act_z[krow * 4 + r][c_local] =
                    1.f / (1.f + __expf(-(acc[r] + bias + (float)gv[r])));
        } else {
            #pragma unroll
            for (int r = 0; r < 4; ++r) {
                act_n[krow * 4 + r][c_local] = acc[r] + bias;
                act_i[krow * 4 + r][c_local] = (float)gv[r];
            }
        }
        __syncthreads();

        // ---- combine (tid<256): h store FIRST, out store second ----
        if (tid < 256) {
            float r0 = act_r[cb][cc],     r1 = act_r[cb][cc + 1];
            float z0 = act_z[cb][cc],     z1 = act_z[cb][cc + 1];
            float a0 = act_i[cb][cc]     + r0 * act_n[cb][cc];
            float a1 = act_i[cb][cc + 1] + r1 * act_n[cb][cc + 1];
            float n0 = 1.f - 2.f / (__expf(2.f * a0) + 1.f);
            float n1 = 1.f - 2.f / (__expf(2.f * a1) + 1.f);
            float hn0 = (1.f - z0) * n0 + z0 * hm0;
            float hn1 = (1.f - z1) * n1 + z1 * hm1;
            hn0 = fminf(fmaxf(hn0, -5.f), 5.f);
            hn1 = fminf(fmaxf(hn1, -5.f), 5.f);
            hm0 = hn0; hm1 = hn1;

            const int bg = bs * MB + cb;
            const int hg = hs * HB + cc;

            f16 p0 = (f16)hn0, p1 = (f16)hn1;
            unsigned pack = (unsigned)__builtin_bit_cast(unsigned short, p0)
                          | ((unsigned)__builtin_bit_cast(unsigned short, p1) << 16);
            store_u32_cohere(hout + (size_t)bg * H_SZ + hg, pack);   // oldest

            *reinterpret_cast<float2*>(
                out + ((size_t)bg * T_SEQ + t) * H_SZ + hg) = make_float2(hn0, hn1);

            if (t == T_SEQ - 1)
                *reinterpret_cast<float2*>(
                    out + (size_t)B_SZ * T_SEQ * H_SZ + (size_t)bg * H_SZ + hg) =
                    make_float2(hn0, hn1);
        }

        // ---- cluster barrier: drain h (out stays in flight), flag, poll ----
        wait_vm1();       // oldest (h sc1 store) retired; out store may linger
        __syncthreads();
        if (t < T_SEQ - 1) {
            if (tid == 0) store_u32_cohere(myflag, (unsigned)(t + 1));
            if (tid < 16) {
                const unsigned int* fp = flags + (size_t)(bs * NHS + tid) * 16;
                int guard = 0;
                unsigned v;
                do {
                    v = load_u32_cohere(fp);
                } while (__any(v < (unsigned)(t + 1)) && ++guard < (1 << 22));
            }
            __syncthreads();
        }
    }
}

// ---------------------------------------------------------------------------
extern "C" void kernel_launch(void* const* d_in, const int* in_sizes, int n_in,
                              void* d_out, int out_size, void* d_ws, size_t ws_size,
                              hipStream_t stream) {
    const float* x    = (const float*)d_in[0];
    const float* h0   = (const float*)d_in[1];
    const float* w_ih = (const float*)d_in[2];
    const float* w_hh = (const float*)d_in[3];
    const float* b_ih = (const float*)d_in[4];
    const float* b_hh = (const float*)d_in[5];
    float* out = (float*)d_out;

    char* p = (char*)d_ws;
    f16* wp16  = (f16*)p;                 p += (size_t)I_SZ * G_SZ * 2;        // 768 KB
    f16* wf16  = (f16*)p;                 p += (size_t)NHS * GB * H_SZ * 2;    // 1.5 MB
    f16* hbuf0 = (f16*)p;                 p += (size_t)B_SZ * H_SZ * 2;        // 128 KB
    f16* hbuf1 = (f16*)p;                 p += (size_t)B_SZ * H_SZ * 2;        // 128 KB
    unsigned int* flags = (unsigned int*)p; p += (size_t)NBS * NHS * 16 * 4;   // 8 KB
    f16* gi = (f16*)p;                    // [T][G][B] f16 = 402 MB

    setup_kernel<<<512, 256, 0, stream>>>(w_ih, w_hh, h0, wp16, wf16, hbuf0, flags);

    proj_kernel<<<T_SEQ * 4, 512, 0, stream>>>(x, wp16, b_ih, gi);

    gru_persist<<<NBS * NHS, NTHR, 0, stream>>>(gi, wf16, h0, b_hh,
                                                hbuf0, hbuf1, flags, out);
}